// Round 1
// baseline (27244.528 us; speedup 1.0000x reference)
//
#include <hip/hip_runtime.h>
#include <hip/hip_bf16.h>
#include <stdint.h>

// ---------------------------------------------------------------------------
// 2-layer GRU (B=64,T=512,IN=256,H=1024) + FC, fp32 I/O.
// Strategy: grid-cooperative persistent kernel. 128 WGs (64 per layer), each
// owns a 16-column chunk of the [64, 3*1024] gate pre-activation for ALL 64
// batch rows (4 waves = 4 MFMA M-tiles of 16). Layers pipelined with 1-step
// skew; one hand-rolled global barrier per step (513 total).
// Precision: W in bf16 (one-time rounding), h state as bf16 hi+lo split
// (~fp32-accurate matvec), x / y0 inputs single bf16, gates in fp32.
// ---------------------------------------------------------------------------

constexpr int TSEQ = 512;
constexpr int NB   = 64;       // batch
constexpr int HD   = 1024;     // hidden
constexpr int IND  = 256;      // input dim
constexpr int NWG  = 128;      // 64 per layer
constexpr int FLAG_STRIDE = 16; // ints -> 64B per flag line

typedef float f32x4  __attribute__((ext_vector_type(4)));
typedef short short8 __attribute__((ext_vector_type(8)));

__device__ __forceinline__ float bf2f(unsigned short u) {
    return __builtin_bit_cast(float, ((unsigned)u) << 16);
}
__device__ __forceinline__ unsigned short f2bf(float f) {
    unsigned u = __builtin_bit_cast(unsigned, f);
    u += 0x7fffu + ((u >> 16) & 1u);     // RNE
    return (unsigned short)(u >> 16);
}
__device__ __forceinline__ float sigm(float x) { return 1.0f / (1.0f + __expf(-x)); }
__device__ __forceinline__ float tanh_fast(float x) { return 1.0f - 2.0f / (1.0f + __expf(2.0f * x)); }

__global__ void convert_w(const float* __restrict__ src, unsigned short* __restrict__ dst, int n) {
    int i = blockIdx.x * blockDim.x + threadIdx.x;
    int stride = gridDim.x * blockDim.x;
    for (; i < n; i += stride) dst[i] = f2bf(src[i]);
}

__global__ __launch_bounds__(256, 1) void gru_main(
    const float* __restrict__ x,
    const unsigned short* __restrict__ wih0,   // [3H][IN]  bf16
    const unsigned short* __restrict__ whh0,   // [3H][H]   bf16
    const unsigned short* __restrict__ wih1,   // [3H][H]   bf16
    const unsigned short* __restrict__ whh1,   // [3H][H]   bf16
    const float* __restrict__ bih0, const float* __restrict__ bhh0,
    const float* __restrict__ bih1, const float* __restrict__ bhh1,
    const float* __restrict__ wfc,  const float* __restrict__ bfc,
    unsigned short* __restrict__ h0hi, unsigned short* __restrict__ h0lo,
    unsigned short* __restrict__ h1hi, unsigned short* __restrict__ h1lo,
    int* __restrict__ flags,
    float* __restrict__ out)
{
    const int wg    = blockIdx.x;
    const int layer = wg >> 6;            // 0: GRU layer 0, 1: GRU layer 1
    const int cc    = wg & 63;            // column chunk within layer
    const int jb    = cc << 4;            // column base (16 cols per WG)
    const int tid   = threadIdx.x;
    const int wave  = tid >> 6;
    const int lane  = tid & 63;
    const int l15   = lane & 15;
    const int kg8   = (lane >> 4) << 3;   // K sub-offset 0/8/16/24
    const int arow  = (wave << 4) + l15;  // A-operand batch row for loads

    const unsigned short* Whh = layer ? whh1 : whh0;
    const unsigned short* Wih = layer ? wih1 : wih0;
    const float* bih = layer ? bih1 : bih0;
    const float* bhh = layer ? bhh1 : bhh0;
    unsigned short* hhi = layer ? h1hi : h0hi;
    unsigned short* hlo = layer ? h1lo : h0lo;

    const int jg = jb + l15;              // this lane's output column (B col)
    const int KW = layer ? HD : IND;      // K of W_ih for this layer
    // B-operand row bases: W rows jg (r), H+jg (z), 2H+jg (n); contiguous in k.
    const unsigned short* WhhR = Whh + (size_t)jg          * HD + kg8;
    const unsigned short* WhhZ = Whh + (size_t)(HD   + jg) * HD + kg8;
    const unsigned short* WhhN = Whh + (size_t)(2*HD + jg) * HD + kg8;
    const unsigned short* WihR = Wih + (size_t)jg          * KW + kg8;
    const unsigned short* WihZ = Wih + (size_t)(HD   + jg) * KW + kg8;
    const unsigned short* WihN = Wih + (size_t)(2*HD + jg) * KW + kg8;

    const float bias_r  = bih[jg]        + bhh[jg];
    const float bias_z  = bih[HD + jg]   + bhh[HD + jg];
    const float bias_nx = bih[2*HD + jg];
    const float bias_nh = bhh[2*HD + jg];

    for (int iter = 0; iter <= TSEQ; ++iter) {
        const bool active = layer ? (iter >= 1) : (iter < TSEQ);
        if (active) {
            const int t     = layer ? (iter - 1) : iter;
            const int rs    = (t + 1) & 1;    // slot holding h(t-1)
            const int wslot = t & 1;          // slot we write h(t) into
            const unsigned short* hrhi = hhi + rs * (NB * HD);
            const unsigned short* hrlo = hlo + rs * (NB * HD);

            f32x4 ar  = {0.f, 0.f, 0.f, 0.f};
            f32x4 az  = {0.f, 0.f, 0.f, 0.f};
            f32x4 ahn = {0.f, 0.f, 0.f, 0.f};
            f32x4 axn = {0.f, 0.f, 0.f, 0.f};

            // ---- recurrent segment: K=1024, A = h(t-1) as hi+lo bf16 ----
            {
                const unsigned short* Ahi = hrhi + (size_t)arow * HD + kg8;
                const unsigned short* Alo = hrlo + (size_t)arow * HD + kg8;
                #pragma unroll 4
                for (int k0 = 0; k0 < HD; k0 += 32) {
                    short8 ahi = *(const short8*)(Ahi + k0);
                    short8 alo = *(const short8*)(Alo + k0);
                    short8 br  = *(const short8*)(WhhR + k0);
                    short8 bz  = *(const short8*)(WhhZ + k0);
                    short8 bn  = *(const short8*)(WhhN + k0);
                    ar  = __builtin_amdgcn_mfma_f32_16x16x32_bf16(ahi, br, ar, 0, 0, 0);
                    az  = __builtin_amdgcn_mfma_f32_16x16x32_bf16(ahi, bz, az, 0, 0, 0);
                    ahn = __builtin_amdgcn_mfma_f32_16x16x32_bf16(ahi, bn, ahn, 0, 0, 0);
                    ar  = __builtin_amdgcn_mfma_f32_16x16x32_bf16(alo, br, ar, 0, 0, 0);
                    az  = __builtin_amdgcn_mfma_f32_16x16x32_bf16(alo, bz, az, 0, 0, 0);
                    ahn = __builtin_amdgcn_mfma_f32_16x16x32_bf16(alo, bn, ahn, 0, 0, 0);
                }
            }
            // ---- input segment ----
            if (layer == 0) {
                // A from x[b][t][k] fp32, converted on the fly; K=256
                const float* xb = x + ((size_t)arow * TSEQ + t) * IND + kg8;
                #pragma unroll
                for (int k0 = 0; k0 < IND; k0 += 32) {
                    float4 xa = *(const float4*)(xb + k0);
                    float4 xc = *(const float4*)(xb + k0 + 4);
                    short8 af;
                    af[0] = (short)f2bf(xa.x); af[1] = (short)f2bf(xa.y);
                    af[2] = (short)f2bf(xa.z); af[3] = (short)f2bf(xa.w);
                    af[4] = (short)f2bf(xc.x); af[5] = (short)f2bf(xc.y);
                    af[6] = (short)f2bf(xc.z); af[7] = (short)f2bf(xc.w);
                    short8 br = *(const short8*)(WihR + k0);
                    short8 bz = *(const short8*)(WihZ + k0);
                    short8 bn = *(const short8*)(WihN + k0);
                    ar  = __builtin_amdgcn_mfma_f32_16x16x32_bf16(af, br, ar, 0, 0, 0);
                    az  = __builtin_amdgcn_mfma_f32_16x16x32_bf16(af, bz, az, 0, 0, 0);
                    axn = __builtin_amdgcn_mfma_f32_16x16x32_bf16(af, bn, axn, 0, 0, 0);
                }
            } else {
                // A from y0(t) = h0(t) hi (written by layer-0 WGs into slot t&1); K=1024
                const unsigned short* yb = h0hi + (size_t)wslot * (NB * HD) + (size_t)arow * HD + kg8;
                #pragma unroll 4
                for (int k0 = 0; k0 < HD; k0 += 32) {
                    short8 ay = *(const short8*)(yb + k0);
                    short8 br = *(const short8*)(WihR + k0);
                    short8 bz = *(const short8*)(WihZ + k0);
                    short8 bn = *(const short8*)(WihN + k0);
                    ar  = __builtin_amdgcn_mfma_f32_16x16x32_bf16(ay, br, ar, 0, 0, 0);
                    az  = __builtin_amdgcn_mfma_f32_16x16x32_bf16(ay, bz, az, 0, 0, 0);
                    axn = __builtin_amdgcn_mfma_f32_16x16x32_bf16(ay, bn, axn, 0, 0, 0);
                }
            }

            // ---- gates + state update (fp32). D map: row=(lane>>4)*4+e, col=lane&15.
            {
                unsigned short* hwhi = hhi + (size_t)wslot * (NB * HD);
                unsigned short* hwlo = hlo + (size_t)wslot * (NB * HD);
                #pragma unroll
                for (int e = 0; e < 4; ++e) {
                    const int bat = (wave << 4) + ((lane >> 4) << 2) + e;
                    const size_t idx = (size_t)bat * HD + jg;
                    float r = sigm(ar[e] + bias_r);
                    float z = sigm(az[e] + bias_z);
                    float n = tanh_fast(axn[e] + bias_nx + r * (ahn[e] + bias_nh));
                    float hold = bf2f(hrhi[idx]) + bf2f(hrlo[idx]);
                    float hnew = (1.0f - z) * n + z * hold;
                    unsigned short hi_ = f2bf(hnew);
                    hwhi[idx] = hi_;
                    hwlo[idx] = f2bf(hnew - bf2f(hi_));
                }
            }
        }

        // ---- global barrier: release fence, stamp own flag, poll all flags ----
        __threadfence();
        __syncthreads();
        if (tid == 0)
            __hip_atomic_store(&flags[wg * FLAG_STRIDE], iter + 1,
                               __ATOMIC_RELAXED, __HIP_MEMORY_SCOPE_AGENT);
        if (tid < NWG) {
            int spins = 0;
            while (__hip_atomic_load(&flags[tid * FLAG_STRIDE],
                                     __ATOMIC_RELAXED, __HIP_MEMORY_SCOPE_AGENT) <= iter) {
                __builtin_amdgcn_s_sleep(2);
                if (++spins > (1 << 19)) break;   // safety valve: fail loud, not hung
            }
        }
        __syncthreads();
        __threadfence();
    }

    // ---- deterministic FC tail by a single WG ----
    if (wg == 64) {
        const int fslot = (TSEQ - 1) & 1;
        const unsigned short* hf_hi = h1hi + (size_t)fslot * (NB * HD);
        const unsigned short* hf_lo = h1lo + (size_t)fslot * (NB * HD);
        const int bat  = tid & 63;
        const int part = tid >> 6;                 // 4 K-partitions of 256
        const int k0   = part * (HD / 4);
        float s = 0.0f;
        for (int k = 0; k < HD / 4; ++k) {
            size_t idx = (size_t)bat * HD + k0 + k;
            s += (bf2f(hf_hi[idx]) + bf2f(hf_lo[idx])) * wfc[k0 + k];
        }
        __shared__ float red[256];
        red[tid] = s;
        __syncthreads();
        if (tid < 64)
            out[tid] = red[tid] + red[tid + 64] + red[tid + 128] + red[tid + 192] + bfc[0];
    }
}

extern "C" void kernel_launch(void* const* d_in, const int* in_sizes, int n_in,
                              void* d_out, int out_size, void* d_ws, size_t ws_size,
                              hipStream_t stream) {
    const float* x    = (const float*)d_in[0];
    const float* Wih0 = (const float*)d_in[1];
    const float* Whh0 = (const float*)d_in[2];
    const float* bih0 = (const float*)d_in[3];
    const float* bhh0 = (const float*)d_in[4];
    const float* Wih1 = (const float*)d_in[5];
    const float* Whh1 = (const float*)d_in[6];
    const float* bih1 = (const float*)d_in[7];
    const float* bhh1 = (const float*)d_in[8];
    const float* Wfc  = (const float*)d_in[9];
    const float* bfc  = (const float*)d_in[10];
    float* out = (float*)d_out;

    char* ws = (char*)d_ws;
    size_t off = 0;
    int* flags = (int*)(ws + off);                 off += (size_t)NWG * FLAG_STRIDE * 4;
    unsigned short* h0hi = (unsigned short*)(ws + off); off += (size_t)2 * NB * HD * 2;
    unsigned short* h0lo = (unsigned short*)(ws + off); off += (size_t)2 * NB * HD * 2;
    unsigned short* h1hi = (unsigned short*)(ws + off); off += (size_t)2 * NB * HD * 2;
    unsigned short* h1lo = (unsigned short*)(ws + off); off += (size_t)2 * NB * HD * 2;
    size_t zero_bytes = off;                       // flags + h buffers get zeroed
    unsigned short* wih0b = (unsigned short*)(ws + off); off += (size_t)3 * HD * IND * 2;
    unsigned short* whh0b = (unsigned short*)(ws + off); off += (size_t)3 * HD * HD * 2;
    unsigned short* wih1b = (unsigned short*)(ws + off); off += (size_t)3 * HD * HD * 2;
    unsigned short* whh1b = (unsigned short*)(ws + off); off += (size_t)3 * HD * HD * 2;
    if (off > ws_size) return;  // insufficient workspace -> loud validation failure

    hipMemsetAsync(d_ws, 0, zero_bytes, stream);
    hipMemsetAsync(d_out, 0, (size_t)out_size * sizeof(float), stream);

    convert_w<<<512, 256, 0, stream>>>(Wih0, wih0b, 3 * HD * IND);
    convert_w<<<512, 256, 0, stream>>>(Whh0, whh0b, 3 * HD * HD);
    convert_w<<<512, 256, 0, stream>>>(Wih1, wih1b, 3 * HD * HD);
    convert_w<<<512, 256, 0, stream>>>(Whh1, whh1b, 3 * HD * HD);

    gru_main<<<NWG, 256, 0, stream>>>(x, wih0b, whh0b, wih1b, whh1b,
                                      bih0, bhh0, bih1, bhh1, Wfc, bfc,
                                      h0hi, h0lo, h1hi, h1lo, flags, out);
}

// Round 3
// 25685.568 us; speedup vs baseline: 1.0607x; 1.0607x over previous
//
#include <hip/hip_runtime.h>
#include <hip/hip_bf16.h>
#include <stdint.h>

// ---------------------------------------------------------------------------
// 2-layer GRU (B=64,T=512,IN=256,H=1024) + FC, fp32 I/O.
// Persistent grid-cooperative kernel, 128 WGs (64/layer), 1-step layer skew.
// R3: fence-free barrier with COMPILER-MANAGED coherent accesses:
//   - cross-WG data (h planes, flags) via __hip_atomic_load/store relaxed
//     agent-scope -> sc0/sc1 (L1/L2-bypassing, coherent at L3); never dirty
//     in any L2, so no buffer_wbl2/inv anywhere; W stays warm in L2.
//   - L3 latency hidden by plain-HIP rolling prefetch (depth 8, compile-time
//     indices); W/x are plain cached loads the compiler pipelines.
//   - Only asm: one s_waitcnt vmcnt(0) (release drain) per iteration.
// Precision: W bf16, h carried as bf16 hi+lo planes, gates fp32.
// ---------------------------------------------------------------------------

constexpr int TSEQ = 512;
constexpr int NB   = 64;
constexpr int HD   = 1024;
constexpr int IND  = 256;
constexpr int NWG  = 128;
constexpr int FS   = 16;   // flag stride in ints (64B lines)

typedef float f32x4  __attribute__((ext_vector_type(4)));
typedef short short8 __attribute__((ext_vector_type(8)));
typedef unsigned long long u64;
typedef unsigned long long u64x2 __attribute__((ext_vector_type(2)));

__device__ __forceinline__ float bf2f(unsigned u) {
    return __builtin_bit_cast(float, u << 16);
}
__device__ __forceinline__ unsigned short f2bf(float f) {
    unsigned u = __builtin_bit_cast(unsigned, f);
    u += 0x7fffu + ((u >> 16) & 1u);     // RNE
    return (unsigned short)(u >> 16);
}
__device__ __forceinline__ float sigm(float x) { return 1.0f / (1.0f + __expf(-x)); }
__device__ __forceinline__ float tanh_fast(float x) { return 1.0f - 2.0f / (1.0f + __expf(2.0f * x)); }

// Coherent (agent-scope, L3) accesses — compiler-managed scheduling/waits.
__device__ __forceinline__ u64 cload64(const unsigned short* p) {
    return __hip_atomic_load((const u64*)p, __ATOMIC_RELAXED, __HIP_MEMORY_SCOPE_AGENT);
}
__device__ __forceinline__ unsigned short cload16(const unsigned short* p) {
    return __hip_atomic_load(p, __ATOMIC_RELAXED, __HIP_MEMORY_SCOPE_AGENT);
}
__device__ __forceinline__ void cstore16(unsigned short* p, unsigned short v) {
    __hip_atomic_store(p, v, __ATOMIC_RELAXED, __HIP_MEMORY_SCOPE_AGENT);
}
__device__ __forceinline__ short8 mk8(u64 a, u64 b) {
    u64x2 t; t.x = a; t.y = b;
    return __builtin_bit_cast(short8, t);
}

#define MFMA(a, b, c) __builtin_amdgcn_mfma_f32_16x16x32_bf16((a), (b), (c), 0, 0, 0)

__global__ void convert_w(const float* __restrict__ src, unsigned short* __restrict__ dst, int n) {
    int i = blockIdx.x * blockDim.x + threadIdx.x;
    int stride = gridDim.x * blockDim.x;
    for (; i < n; i += stride) dst[i] = f2bf(src[i]);
}

__global__ __launch_bounds__(256, 1) void gru_main(
    const float* __restrict__ x,
    const unsigned short* __restrict__ wih0,
    const unsigned short* __restrict__ whh0,
    const unsigned short* __restrict__ wih1,
    const unsigned short* __restrict__ whh1,
    const float* __restrict__ bih0, const float* __restrict__ bhh0,
    const float* __restrict__ bih1, const float* __restrict__ bhh1,
    const float* __restrict__ wfc,  const float* __restrict__ bfc,
    unsigned short* __restrict__ h0hi, unsigned short* __restrict__ h0lo,
    unsigned short* __restrict__ h1hi, unsigned short* __restrict__ h1lo,
    int* __restrict__ flags,
    float* __restrict__ out)
{
    const int wg    = blockIdx.x;
    const int layer = wg >> 6;
    const int cc    = wg & 63;
    const int jb    = cc << 4;
    const int tid   = threadIdx.x;
    const int wave  = tid >> 6;
    const int lane  = tid & 63;
    const int l15   = lane & 15;
    const int kg8   = (lane >> 4) << 3;
    const int arow  = (wave << 4) + l15;

    const unsigned short* Whh = layer ? whh1 : whh0;
    const unsigned short* Wih = layer ? wih1 : wih0;
    const float* bih = layer ? bih1 : bih0;
    const float* bhh = layer ? bhh1 : bhh0;
    unsigned short* hhi = layer ? h1hi : h0hi;
    unsigned short* hlo = layer ? h1lo : h0lo;

    const int jg = jb + l15;
    const int KW = layer ? HD : IND;
    const unsigned short* WhhR = Whh + (size_t)jg          * HD + kg8;
    const unsigned short* WhhZ = Whh + (size_t)(HD   + jg) * HD + kg8;
    const unsigned short* WhhN = Whh + (size_t)(2*HD + jg) * HD + kg8;
    const unsigned short* WihR = Wih + (size_t)jg          * KW + kg8;
    const unsigned short* WihZ = Wih + (size_t)(HD   + jg) * KW + kg8;
    const unsigned short* WihN = Wih + (size_t)(2*HD + jg) * KW + kg8;

    const float bias_r  = bih[jg]        + bhh[jg];
    const float bias_z  = bih[HD + jg]   + bhh[HD + jg];
    const float bias_nx = bih[2*HD + jg];
    const float bias_nh = bhh[2*HD + jg];

    for (int iter = 0; iter <= TSEQ; ++iter) {
        const bool active = layer ? (iter >= 1) : (iter < TSEQ);
        if (active) {
            const int t     = layer ? (iter - 1) : iter;
            const int rs    = (t + 1) & 1;
            const int wslot = t & 1;
            const unsigned short* hrhi = hhi + rs * (NB * HD);
            const unsigned short* hrlo = hlo + rs * (NB * HD);

            f32x4 ar  = {0.f, 0.f, 0.f, 0.f};
            f32x4 az  = {0.f, 0.f, 0.f, 0.f};
            f32x4 ahn = {0.f, 0.f, 0.f, 0.f};
            f32x4 axn = {0.f, 0.f, 0.f, 0.f};

            // ---- prefetch old h at this thread's 4 output cells (coherent) ----
            unsigned short hoh[4], hol[4];
            #pragma unroll
            for (int e = 0; e < 4; ++e) {
                const int bat = (wave << 4) + ((lane >> 4) << 2) + e;
                hoh[e] = cload16(hrhi + (size_t)bat * HD + jg);
                hol[e] = cload16(hrlo + (size_t)bat * HD + jg);
            }

            const unsigned short* pAh = hrhi + (size_t)arow * HD + kg8;
            const unsigned short* pAl = hrlo + (size_t)arow * HD + kg8;

            if (layer == 0) {
                // ===== recurrent: 32 chunks, rolling prefetch depth 8 =====
                constexpr int D0 = 8;
                u64 ah0[D0], ah1[D0], al0[D0], al1[D0];
                #pragma unroll
                for (int i = 0; i < D0; ++i) {
                    ah0[i] = cload64(pAh + i * 32); ah1[i] = cload64(pAh + i * 32 + 4);
                    al0[i] = cload64(pAl + i * 32); al1[i] = cload64(pAl + i * 32 + 4);
                }
                #pragma unroll
                for (int k = 0; k < 32; ++k) {
                    const int s = k & (D0 - 1);
                    short8 Ahi = mk8(ah0[s], ah1[s]);
                    short8 Alo = mk8(al0[s], al1[s]);
                    short8 br = *(const short8*)(WhhR + k * 32);
                    short8 bz = *(const short8*)(WhhZ + k * 32);
                    short8 bn = *(const short8*)(WhhN + k * 32);
                    ar  = MFMA(Ahi, br, ar);  ar  = MFMA(Alo, br, ar);
                    az  = MFMA(Ahi, bz, az);  az  = MFMA(Alo, bz, az);
                    ahn = MFMA(Ahi, bn, ahn); ahn = MFMA(Alo, bn, ahn);
                    if (k + D0 < 32) {
                        ah0[s] = cload64(pAh + (k + D0) * 32);
                        ah1[s] = cload64(pAh + (k + D0) * 32 + 4);
                        al0[s] = cload64(pAl + (k + D0) * 32);
                        al1[s] = cload64(pAl + (k + D0) * 32 + 4);
                    }
                }
                // ===== input projection: 8 chunks, plain cached loads =====
                const float* px = x + ((size_t)arow * TSEQ + t) * IND + kg8;
                #pragma unroll
                for (int k = 0; k < 8; ++k) {
                    float4 xa = *(const float4*)(px + k * 32);
                    float4 xc = *(const float4*)(px + k * 32 + 4);
                    short8 af;
                    af[0] = (short)f2bf(xa.x); af[1] = (short)f2bf(xa.y);
                    af[2] = (short)f2bf(xa.z); af[3] = (short)f2bf(xa.w);
                    af[4] = (short)f2bf(xc.x); af[5] = (short)f2bf(xc.y);
                    af[6] = (short)f2bf(xc.z); af[7] = (short)f2bf(xc.w);
                    short8 br = *(const short8*)(WihR + k * 32);
                    short8 bz = *(const short8*)(WihZ + k * 32);
                    short8 bn = *(const short8*)(WihN + k * 32);
                    ar  = MFMA(af, br, ar);
                    az  = MFMA(af, bz, az);
                    axn = MFMA(af, bn, axn);
                }
            } else {
                // ===== fused recurrent + input (y0): 32 chunks, depth 8 =====
                const unsigned short* pAy = h0hi + (size_t)wslot * (NB * HD)
                                                 + (size_t)arow * HD + kg8;
                constexpr int D1 = 8;
                u64 ah0[D1], ah1[D1], al0[D1], al1[D1], ay0[D1], ay1[D1];
                #pragma unroll
                for (int i = 0; i < D1; ++i) {
                    ah0[i] = cload64(pAh + i * 32); ah1[i] = cload64(pAh + i * 32 + 4);
                    al0[i] = cload64(pAl + i * 32); al1[i] = cload64(pAl + i * 32 + 4);
                    ay0[i] = cload64(pAy + i * 32); ay1[i] = cload64(pAy + i * 32 + 4);
                }
                #pragma unroll
                for (int k = 0; k < 32; ++k) {
                    const int s = k & (D1 - 1);
                    short8 Ahi = mk8(ah0[s], ah1[s]);
                    short8 Alo = mk8(al0[s], al1[s]);
                    short8 Ay  = mk8(ay0[s], ay1[s]);
                    short8 hr = *(const short8*)(WhhR + k * 32);
                    short8 hz = *(const short8*)(WhhZ + k * 32);
                    short8 hn = *(const short8*)(WhhN + k * 32);
                    short8 ir = *(const short8*)(WihR + k * 32);
                    short8 iz = *(const short8*)(WihZ + k * 32);
                    short8 in_ = *(const short8*)(WihN + k * 32);
                    ar  = MFMA(Ahi, hr, ar);  ar  = MFMA(Alo, hr, ar);
                    ar  = MFMA(Ay,  ir, ar);
                    az  = MFMA(Ahi, hz, az);  az  = MFMA(Alo, hz, az);
                    az  = MFMA(Ay,  iz, az);
                    ahn = MFMA(Ahi, hn, ahn); ahn = MFMA(Alo, hn, ahn);
                    axn = MFMA(Ay,  in_, axn);
                    if (k + D1 < 32) {
                        ah0[s] = cload64(pAh + (k + D1) * 32);
                        ah1[s] = cload64(pAh + (k + D1) * 32 + 4);
                        al0[s] = cload64(pAl + (k + D1) * 32);
                        al1[s] = cload64(pAl + (k + D1) * 32 + 4);
                        ay0[s] = cload64(pAy + (k + D1) * 32);
                        ay1[s] = cload64(pAy + (k + D1) * 32 + 4);
                    }
                }
            }

            // ---- gates + state update + coherent (write-through) store ----
            unsigned short* hwhi = hhi + wslot * (NB * HD);
            unsigned short* hwlo = hlo + wslot * (NB * HD);
            #pragma unroll
            for (int e = 0; e < 4; ++e) {
                const int bat = (wave << 4) + ((lane >> 4) << 2) + e;
                const size_t idx = (size_t)bat * HD + jg;
                float r = sigm(ar[e] + bias_r);
                float z = sigm(az[e] + bias_z);
                float n = tanh_fast(axn[e] + bias_nx + r * (ahn[e] + bias_nh));
                float hold = bf2f((unsigned)hoh[e]) + bf2f((unsigned)hol[e]);
                float hnew = (1.0f - z) * n + z * hold;
                unsigned short hi_ = f2bf(hnew);
                cstore16(hwhi + idx, hi_);
                cstore16(hwlo + idx, f2bf(hnew - bf2f((unsigned)hi_)));
            }
        }

        // ---- fence-free global barrier ----
        // Release: drain write-through stores (acked at coherence point).
        asm volatile("s_waitcnt vmcnt(0)" ::: "memory");
        __syncthreads();
        if (tid == 0)
            __hip_atomic_store(&flags[wg * FS], iter + 1,
                               __ATOMIC_RELAXED, __HIP_MEMORY_SCOPE_AGENT);
        if (tid < NWG) {
            int spins = 0;
            while (__hip_atomic_load(&flags[tid * FS],
                                     __ATOMIC_RELAXED, __HIP_MEMORY_SCOPE_AGENT) <= iter) {
                __builtin_amdgcn_s_sleep(2);
                if (++spins > (1 << 20)) break;   // fail loud, never hang
            }
        }
        __syncthreads();
    }

    // ---- deterministic FC tail (single WG, coherent reads) ----
    if (wg == 64) {
        const int fslot = (TSEQ - 1) & 1;
        const unsigned short* hf_hi = h1hi + (size_t)fslot * (NB * HD);
        const unsigned short* hf_lo = h1lo + (size_t)fslot * (NB * HD);
        const int bat  = tid & 63;
        const int part = tid >> 6;
        const int k0   = part * (HD / 4);
        float s = 0.0f;
        for (int k = 0; k < HD / 4; k += 4) {
            u64 vh = cload64(hf_hi + (size_t)bat * HD + k0 + k);
            u64 vl = cload64(hf_lo + (size_t)bat * HD + k0 + k);
            #pragma unroll
            for (int j = 0; j < 4; ++j) {
                unsigned short hh = (unsigned short)(vh >> (16 * j));
                unsigned short ll = (unsigned short)(vl >> (16 * j));
                s += (bf2f((unsigned)hh) + bf2f((unsigned)ll)) * wfc[k0 + k + j];
            }
        }
        __shared__ float red[256];
        red[tid] = s;
        __syncthreads();
        if (tid < 64)
            out[tid] = red[tid] + red[tid + 64] + red[tid + 128] + red[tid + 192] + bfc[0];
    }
}

extern "C" void kernel_launch(void* const* d_in, const int* in_sizes, int n_in,
                              void* d_out, int out_size, void* d_ws, size_t ws_size,
                              hipStream_t stream) {
    const float* x    = (const float*)d_in[0];
    const float* Wih0 = (const float*)d_in[1];
    const float* Whh0 = (const float*)d_in[2];
    const float* bih0 = (const float*)d_in[3];
    const float* bhh0 = (const float*)d_in[4];
    const float* Wih1 = (const float*)d_in[5];
    const float* Whh1 = (const float*)d_in[6];
    const float* bih1 = (const float*)d_in[7];
    const float* bhh1 = (const float*)d_in[8];
    const float* Wfc  = (const float*)d_in[9];
    const float* bfc  = (const float*)d_in[10];
    float* out = (float*)d_out;

    char* ws = (char*)d_ws;
    size_t off = 0;
    int* flags = (int*)(ws + off);                 off += (size_t)NWG * FS * 4;
    unsigned short* h0hi = (unsigned short*)(ws + off); off += (size_t)2 * NB * HD * 2;
    unsigned short* h0lo = (unsigned short*)(ws + off); off += (size_t)2 * NB * HD * 2;
    unsigned short* h1hi = (unsigned short*)(ws + off); off += (size_t)2 * NB * HD * 2;
    unsigned short* h1lo = (unsigned short*)(ws + off); off += (size_t)2 * NB * HD * 2;
    size_t zero_bytes = off;
    unsigned short* wih0b = (unsigned short*)(ws + off); off += (size_t)3 * HD * IND * 2;
    unsigned short* whh0b = (unsigned short*)(ws + off); off += (size_t)3 * HD * HD * 2;
    unsigned short* wih1b = (unsigned short*)(ws + off); off += (size_t)3 * HD * HD * 2;
    unsigned short* whh1b = (unsigned short*)(ws + off); off += (size_t)3 * HD * HD * 2;
    if (off > ws_size) return;

    hipMemsetAsync(d_ws, 0, zero_bytes, stream);
    hipMemsetAsync(d_out, 0, (size_t)out_size * sizeof(float), stream);

    convert_w<<<512, 256, 0, stream>>>(Wih0, wih0b, 3 * HD * IND);
    convert_w<<<512, 256, 0, stream>>>(Whh0, whh0b, 3 * HD * HD);
    convert_w<<<512, 256, 0, stream>>>(Wih1, wih1b, 3 * HD * HD);
    convert_w<<<512, 256, 0, stream>>>(Whh1, whh1b, 3 * HD * HD);

    gru_main<<<NWG, 256, 0, stream>>>(x, wih0b, whh0b, wih1b, whh1b,
                                      bih0, bhh0, bih1, bhh1, Wfc, bfc,
                                      h0hi, h0lo, h1hi, h1lo, flags, out);
}

// Round 4
// 23669.324 us; speedup vs baseline: 1.1510x; 1.0852x over previous
//
#include <hip/hip_runtime.h>
#include <hip/hip_bf16.h>
#include <stdint.h>

// ---------------------------------------------------------------------------
// 2-layer GRU (B=64,T=512,IN=256,H=1024) + FC, fp32 I/O.
// Persistent grid-cooperative kernel, 128 WGs (64/layer), 1-step layer skew.
// R4:
//  (a) K-loop software pipeline pinned with sched_barrier(0) after each
//      prefetch-issue group (R3's pipeline was collapsed by the scheduler:
//      VGPR=108 proved the depth-8 buffers never lived in registers).
//  (b) Barrier = per-iteration arrival counter (atomicAdd at L3 coherence
//      point) + single-thread poll. No flag array, no poll storm, no reset.
// Cross-WG data (h planes) via relaxed agent-scope atomics (sc0/sc1: bypass
// L1/L2, coherent at L3). No cache-maintenance fences anywhere.
// Precision: W bf16, h carried as bf16 hi+lo planes, gates fp32.
// ---------------------------------------------------------------------------

constexpr int TSEQ = 512;
constexpr int NB   = 64;
constexpr int HD   = 1024;
constexpr int IND  = 256;
constexpr int NWG  = 128;
constexpr int FS   = 16;   // arrival-counter stride in ints (64B lines)

typedef float f32x4  __attribute__((ext_vector_type(4)));
typedef short short8 __attribute__((ext_vector_type(8)));
typedef unsigned long long u64;
typedef unsigned long long u64x2 __attribute__((ext_vector_type(2)));

__device__ __forceinline__ float bf2f(unsigned u) {
    return __builtin_bit_cast(float, u << 16);
}
__device__ __forceinline__ unsigned short f2bf(float f) {
    unsigned u = __builtin_bit_cast(unsigned, f);
    u += 0x7fffu + ((u >> 16) & 1u);     // RNE
    return (unsigned short)(u >> 16);
}
__device__ __forceinline__ float sigm(float x) { return 1.0f / (1.0f + __expf(-x)); }
__device__ __forceinline__ float tanh_fast(float x) { return 1.0f - 2.0f / (1.0f + __expf(2.0f * x)); }

__device__ __forceinline__ u64 cload64(const unsigned short* p) {
    return __hip_atomic_load((const u64*)p, __ATOMIC_RELAXED, __HIP_MEMORY_SCOPE_AGENT);
}
__device__ __forceinline__ unsigned short cload16(const unsigned short* p) {
    return __hip_atomic_load(p, __ATOMIC_RELAXED, __HIP_MEMORY_SCOPE_AGENT);
}
__device__ __forceinline__ void cstore16(unsigned short* p, unsigned short v) {
    __hip_atomic_store(p, v, __ATOMIC_RELAXED, __HIP_MEMORY_SCOPE_AGENT);
}
__device__ __forceinline__ short8 mk8(u64 a, u64 b) {
    u64x2 t; t.x = a; t.y = b;
    return __builtin_bit_cast(short8, t);
}

#define MFMA(a, b, c) __builtin_amdgcn_mfma_f32_16x16x32_bf16((a), (b), (c), 0, 0, 0)
#define SB0() __builtin_amdgcn_sched_barrier(0)

__global__ void convert_w(const float* __restrict__ src, unsigned short* __restrict__ dst, int n) {
    int i = blockIdx.x * blockDim.x + threadIdx.x;
    int stride = gridDim.x * blockDim.x;
    for (; i < n; i += stride) dst[i] = f2bf(src[i]);
}

__global__ __launch_bounds__(256, 1) void gru_main(
    const float* __restrict__ x,
    const unsigned short* __restrict__ wih0,
    const unsigned short* __restrict__ whh0,
    const unsigned short* __restrict__ wih1,
    const unsigned short* __restrict__ whh1,
    const float* __restrict__ bih0, const float* __restrict__ bhh0,
    const float* __restrict__ bih1, const float* __restrict__ bhh1,
    const float* __restrict__ wfc,  const float* __restrict__ bfc,
    unsigned short* __restrict__ h0hi, unsigned short* __restrict__ h0lo,
    unsigned short* __restrict__ h1hi, unsigned short* __restrict__ h1lo,
    int* __restrict__ arrive,
    float* __restrict__ out)
{
    const int wg    = blockIdx.x;
    const int layer = wg >> 6;
    const int cc    = wg & 63;
    const int jb    = cc << 4;
    const int tid   = threadIdx.x;
    const int wave  = tid >> 6;
    const int lane  = tid & 63;
    const int l15   = lane & 15;
    const int kg8   = (lane >> 4) << 3;
    const int arow  = (wave << 4) + l15;

    const unsigned short* Whh = layer ? whh1 : whh0;
    const unsigned short* Wih = layer ? wih1 : wih0;
    const float* bih = layer ? bih1 : bih0;
    const float* bhh = layer ? bhh1 : bhh0;
    unsigned short* hhi = layer ? h1hi : h0hi;
    unsigned short* hlo = layer ? h1lo : h0lo;

    const int jg = jb + l15;
    const int KW = layer ? HD : IND;
    const unsigned short* WhhR = Whh + (size_t)jg          * HD + kg8;
    const unsigned short* WhhZ = Whh + (size_t)(HD   + jg) * HD + kg8;
    const unsigned short* WhhN = Whh + (size_t)(2*HD + jg) * HD + kg8;
    const unsigned short* WihR = Wih + (size_t)jg          * KW + kg8;
    const unsigned short* WihZ = Wih + (size_t)(HD   + jg) * KW + kg8;
    const unsigned short* WihN = Wih + (size_t)(2*HD + jg) * KW + kg8;

    const float bias_r  = bih[jg]        + bhh[jg];
    const float bias_z  = bih[HD + jg]   + bhh[HD + jg];
    const float bias_nx = bih[2*HD + jg];
    const float bias_nh = bhh[2*HD + jg];

    for (int iter = 0; iter <= TSEQ; ++iter) {
        const bool active = layer ? (iter >= 1) : (iter < TSEQ);
        if (active) {
            const int t     = layer ? (iter - 1) : iter;
            const int rs    = (t + 1) & 1;
            const int wslot = t & 1;
            const unsigned short* hrhi = hhi + rs * (NB * HD);
            const unsigned short* hrlo = hlo + rs * (NB * HD);

            f32x4 ar  = {0.f, 0.f, 0.f, 0.f};
            f32x4 az  = {0.f, 0.f, 0.f, 0.f};
            f32x4 ahn = {0.f, 0.f, 0.f, 0.f};
            f32x4 axn = {0.f, 0.f, 0.f, 0.f};

            // ---- old h at this thread's 4 output cells (coherent) ----
            unsigned short hoh[4], hol[4];
            #pragma unroll
            for (int e = 0; e < 4; ++e) {
                const int bat = (wave << 4) + ((lane >> 4) << 2) + e;
                hoh[e] = cload16(hrhi + (size_t)bat * HD + jg);
                hol[e] = cload16(hrlo + (size_t)bat * HD + jg);
            }

            const unsigned short* pAh = hrhi + (size_t)arow * HD + kg8;
            const unsigned short* pAl = hrlo + (size_t)arow * HD + kg8;

            if (layer == 0) {
                // ===== recurrent: 32 chunks, pinned rolling prefetch D=6 =====
                constexpr int D = 6;
                u64 ah0[D], ah1[D], al0[D], al1[D];
                #pragma unroll
                for (int i = 0; i < D; ++i) {
                    ah0[i] = cload64(pAh + i * 32); ah1[i] = cload64(pAh + i * 32 + 4);
                    al0[i] = cload64(pAl + i * 32); al1[i] = cload64(pAl + i * 32 + 4);
                }
                SB0();
                #pragma unroll
                for (int k = 0; k < 32; ++k) {
                    const int s = k % D;
                    short8 Ahi = mk8(ah0[s], ah1[s]);
                    short8 Alo = mk8(al0[s], al1[s]);
                    short8 br = *(const short8*)(WhhR + k * 32);
                    short8 bz = *(const short8*)(WhhZ + k * 32);
                    short8 bn = *(const short8*)(WhhN + k * 32);
                    ar  = MFMA(Ahi, br, ar);  ar  = MFMA(Alo, br, ar);
                    az  = MFMA(Ahi, bz, az);  az  = MFMA(Alo, bz, az);
                    ahn = MFMA(Ahi, bn, ahn); ahn = MFMA(Alo, bn, ahn);
                    if (k + D < 32) {
                        ah0[s] = cload64(pAh + (k + D) * 32);
                        ah1[s] = cload64(pAh + (k + D) * 32 + 4);
                        al0[s] = cload64(pAl + (k + D) * 32);
                        al1[s] = cload64(pAl + (k + D) * 32 + 4);
                        SB0();   // pin issue point: loads may not sink below
                    }
                }
                // ===== input projection: 8 chunks, cached loads =====
                const float* px = x + ((size_t)arow * TSEQ + t) * IND + kg8;
                #pragma unroll
                for (int k = 0; k < 8; ++k) {
                    float4 xa = *(const float4*)(px + k * 32);
                    float4 xc = *(const float4*)(px + k * 32 + 4);
                    short8 af;
                    af[0] = (short)f2bf(xa.x); af[1] = (short)f2bf(xa.y);
                    af[2] = (short)f2bf(xa.z); af[3] = (short)f2bf(xa.w);
                    af[4] = (short)f2bf(xc.x); af[5] = (short)f2bf(xc.y);
                    af[6] = (short)f2bf(xc.z); af[7] = (short)f2bf(xc.w);
                    short8 br = *(const short8*)(WihR + k * 32);
                    short8 bz = *(const short8*)(WihZ + k * 32);
                    short8 bn = *(const short8*)(WihN + k * 32);
                    ar  = MFMA(af, br, ar);
                    az  = MFMA(af, bz, az);
                    axn = MFMA(af, bn, axn);
                }
            } else {
                // ===== fused recurrent + input (y0): 32 chunks, pinned D=6 =====
                const unsigned short* pAy = h0hi + (size_t)wslot * (NB * HD)
                                                 + (size_t)arow * HD + kg8;
                constexpr int D = 6;
                u64 ah0[D], ah1[D], al0[D], al1[D], ay0[D], ay1[D];
                #pragma unroll
                for (int i = 0; i < D; ++i) {
                    ah0[i] = cload64(pAh + i * 32); ah1[i] = cload64(pAh + i * 32 + 4);
                    al0[i] = cload64(pAl + i * 32); al1[i] = cload64(pAl + i * 32 + 4);
                    ay0[i] = cload64(pAy + i * 32); ay1[i] = cload64(pAy + i * 32 + 4);
                }
                SB0();
                #pragma unroll
                for (int k = 0; k < 32; ++k) {
                    const int s = k % D;
                    short8 Ahi = mk8(ah0[s], ah1[s]);
                    short8 Alo = mk8(al0[s], al1[s]);
                    short8 Ay  = mk8(ay0[s], ay1[s]);
                    short8 hr = *(const short8*)(WhhR + k * 32);
                    short8 hz = *(const short8*)(WhhZ + k * 32);
                    short8 hn = *(const short8*)(WhhN + k * 32);
                    short8 ir = *(const short8*)(WihR + k * 32);
                    short8 iz = *(const short8*)(WihZ + k * 32);
                    short8 in_ = *(const short8*)(WihN + k * 32);
                    ar  = MFMA(Ahi, hr, ar);  ar  = MFMA(Alo, hr, ar);
                    ar  = MFMA(Ay,  ir, ar);
                    az  = MFMA(Ahi, hz, az);  az  = MFMA(Alo, hz, az);
                    az  = MFMA(Ay,  iz, az);
                    ahn = MFMA(Ahi, hn, ahn); ahn = MFMA(Alo, hn, ahn);
                    axn = MFMA(Ay,  in_, axn);
                    if (k + D < 32) {
                        ah0[s] = cload64(pAh + (k + D) * 32);
                        ah1[s] = cload64(pAh + (k + D) * 32 + 4);
                        al0[s] = cload64(pAl + (k + D) * 32);
                        al1[s] = cload64(pAl + (k + D) * 32 + 4);
                        ay0[s] = cload64(pAy + (k + D) * 32);
                        ay1[s] = cload64(pAy + (k + D) * 32 + 4);
                        SB0();   // pin issue point
                    }
                }
            }

            // ---- gates + state update + coherent (write-through) store ----
            unsigned short* hwhi = hhi + wslot * (NB * HD);
            unsigned short* hwlo = hlo + wslot * (NB * HD);
            #pragma unroll
            for (int e = 0; e < 4; ++e) {
                const int bat = (wave << 4) + ((lane >> 4) << 2) + e;
                const size_t idx = (size_t)bat * HD + jg;
                float r = sigm(ar[e] + bias_r);
                float z = sigm(az[e] + bias_z);
                float n = tanh_fast(axn[e] + bias_nx + r * (ahn[e] + bias_nh));
                float hold = bf2f((unsigned)hoh[e]) + bf2f((unsigned)hol[e]);
                float hnew = (1.0f - z) * n + z * hold;
                unsigned short hi_ = f2bf(hnew);
                cstore16(hwhi + idx, hi_);
                cstore16(hwlo + idx, f2bf(hnew - bf2f((unsigned)hi_)));
            }
        }

        // ---- barrier: drain stores, count arrivals at L3, single poller ----
        asm volatile("s_waitcnt vmcnt(0)" ::: "memory");  // h stores at L3
        __syncthreads();                                   // whole WG drained
        if (tid == 0) {
            atomicAdd(&arrive[iter * FS], 1);              // RMW at coherence point
            int spins = 0;
            while (__hip_atomic_load(&arrive[iter * FS],
                                     __ATOMIC_RELAXED, __HIP_MEMORY_SCOPE_AGENT) < NWG) {
                __builtin_amdgcn_s_sleep(1);
                if (++spins > (1 << 20)) break;            // fail loud, never hang
            }
        }
        __syncthreads();
    }

    // ---- deterministic FC tail (single WG, coherent reads) ----
    if (wg == 64) {
        const int fslot = (TSEQ - 1) & 1;
        const unsigned short* hf_hi = h1hi + (size_t)fslot * (NB * HD);
        const unsigned short* hf_lo = h1lo + (size_t)fslot * (NB * HD);
        const int bat  = tid & 63;
        const int part = tid >> 6;
        const int k0   = part * (HD / 4);
        float s = 0.0f;
        for (int k = 0; k < HD / 4; k += 4) {
            u64 vh = cload64(hf_hi + (size_t)bat * HD + k0 + k);
            u64 vl = cload64(hf_lo + (size_t)bat * HD + k0 + k);
            #pragma unroll
            for (int j = 0; j < 4; ++j) {
                unsigned short hh = (unsigned short)(vh >> (16 * j));
                unsigned short ll = (unsigned short)(vl >> (16 * j));
                s += (bf2f((unsigned)hh) + bf2f((unsigned)ll)) * wfc[k0 + k + j];
            }
        }
        __shared__ float red[256];
        red[tid] = s;
        __syncthreads();
        if (tid < 64)
            out[tid] = red[tid] + red[tid + 64] + red[tid + 128] + red[tid + 192] + bfc[0];
    }
}

extern "C" void kernel_launch(void* const* d_in, const int* in_sizes, int n_in,
                              void* d_out, int out_size, void* d_ws, size_t ws_size,
                              hipStream_t stream) {
    const float* x    = (const float*)d_in[0];
    const float* Wih0 = (const float*)d_in[1];
    const float* Whh0 = (const float*)d_in[2];
    const float* bih0 = (const float*)d_in[3];
    const float* bhh0 = (const float*)d_in[4];
    const float* Wih1 = (const float*)d_in[5];
    const float* Whh1 = (const float*)d_in[6];
    const float* bih1 = (const float*)d_in[7];
    const float* bhh1 = (const float*)d_in[8];
    const float* Wfc  = (const float*)d_in[9];
    const float* bfc  = (const float*)d_in[10];
    float* out = (float*)d_out;

    char* ws = (char*)d_ws;
    size_t off = 0;
    int* arrive = (int*)(ws + off);                off += (size_t)(TSEQ + 1) * FS * 4;
    unsigned short* h0hi = (unsigned short*)(ws + off); off += (size_t)2 * NB * HD * 2;
    unsigned short* h0lo = (unsigned short*)(ws + off); off += (size_t)2 * NB * HD * 2;
    unsigned short* h1hi = (unsigned short*)(ws + off); off += (size_t)2 * NB * HD * 2;
    unsigned short* h1lo = (unsigned short*)(ws + off); off += (size_t)2 * NB * HD * 2;
    size_t zero_bytes = off;
    unsigned short* wih0b = (unsigned short*)(ws + off); off += (size_t)3 * HD * IND * 2;
    unsigned short* whh0b = (unsigned short*)(ws + off); off += (size_t)3 * HD * HD * 2;
    unsigned short* wih1b = (unsigned short*)(ws + off); off += (size_t)3 * HD * HD * 2;
    unsigned short* whh1b = (unsigned short*)(ws + off); off += (size_t)3 * HD * HD * 2;
    if (off > ws_size) return;

    hipMemsetAsync(d_ws, 0, zero_bytes, stream);
    hipMemsetAsync(d_out, 0, (size_t)out_size * sizeof(float), stream);

    convert_w<<<512, 256, 0, stream>>>(Wih0, wih0b, 3 * HD * IND);
    convert_w<<<512, 256, 0, stream>>>(Whh0, whh0b, 3 * HD * HD);
    convert_w<<<512, 256, 0, stream>>>(Wih1, wih1b, 3 * HD * HD);
    convert_w<<<512, 256, 0, stream>>>(Whh1, whh1b, 3 * HD * HD);

    gru_main<<<NWG, 256, 0, stream>>>(x, wih0b, whh0b, wih1b, whh1b,
                                      bih0, bhh0, bih1, bhh1, Wfc, bfc,
                                      h0hi, h0lo, h1hi, h1lo, arrive, out);
}

// Round 5
// 18528.523 us; speedup vs baseline: 1.4704x; 1.2775x over previous
//
#include <hip/hip_runtime.h>
#include <hip/hip_bf16.h>
#include <stdint.h>

// ---------------------------------------------------------------------------
// 2-layer GRU (B=64,T=512,IN=256,H=1024) + FC, fp32 I/O.
// Persistent grid-cooperative kernel, 128 WGs (64/layer), 1-step layer skew.
// R5: un-collapsible software pipeline. Every K-loop VMEM op is asm volatile
// with an explicit dest tuple (forced live range; compiler cannot serialize).
// One in-order counted-vmcnt stream per body:
//   prologue: A0 W0 A1 W1 A2 W2 A3
//   body c:   issue W(c+3), A(c+4); s_waitcnt vmcnt(K) -> drains A(c),W(c);
//             MFMA on slot c.  A-flight = 4 bodies (~800cy > L3), W = 3.
// A loads carry sc0 sc1 (L1/L2-bypass, coherent at L3); W loads plain (L2).
// Barrier: per-iteration arrival counter (R4-proven).
// Precision: W bf16, h as bf16 hi+lo planes, gates fp32.
// ---------------------------------------------------------------------------

constexpr int TSEQ = 512;
constexpr int NB   = 64;
constexpr int HD   = 1024;
constexpr int IND  = 256;
constexpr int NWG  = 128;
constexpr int FS   = 16;

typedef float f32x4  __attribute__((ext_vector_type(4)));
typedef short short8 __attribute__((ext_vector_type(8)));

__device__ __forceinline__ float bf2f(unsigned u) {
    return __builtin_bit_cast(float, u << 16);
}
__device__ __forceinline__ unsigned short f2bf(float f) {
    unsigned u = __builtin_bit_cast(unsigned, f);
    u += 0x7fffu + ((u >> 16) & 1u);     // RNE
    return (unsigned short)(u >> 16);
}
__device__ __forceinline__ float sigm(float x) { return 1.0f / (1.0f + __expf(-x)); }
__device__ __forceinline__ float tanh_fast(float x) { return 1.0f - 2.0f / (1.0f + __expf(2.0f * x)); }

__device__ __forceinline__ unsigned short cload16(const unsigned short* p) {
    return __hip_atomic_load(p, __ATOMIC_RELAXED, __HIP_MEMORY_SCOPE_AGENT);
}
__device__ __forceinline__ void cstore16(unsigned short* p, unsigned short v) {
    __hip_atomic_store(p, v, __ATOMIC_RELAXED, __HIP_MEMORY_SCOPE_AGENT);
}

#define MFMA(a, b, c) __builtin_amdgcn_mfma_f32_16x16x32_bf16((a), (b), (c), 0, 0, 0)

// Coherent A-load (L3), 16B, immediate chunk offset.
#define LDA16(dst, base, imm) \
    asm volatile("global_load_dwordx4 %0, %1, off offset:%2 sc0 sc1" \
                 : "=v"(dst) : "v"(base), "i"(imm))
// Cached W-load (L2), 16B.
#define LDW16(dst, base, imm) \
    asm volatile("global_load_dwordx4 %0, %1, off offset:%2" \
                 : "=v"(dst) : "v"(base), "i"(imm))
// Counted wait + scheduler pin (rule #18: MFMA must not hoist above).
#define VWAIT(n) do { asm volatile("s_waitcnt vmcnt(" #n ")" ::: "memory"); \
                      __builtin_amdgcn_sched_barrier(0); } while (0)
#define CFENCE() asm volatile("" ::: "memory")

__global__ void convert_w(const float* __restrict__ src, unsigned short* __restrict__ dst, int n) {
    int i = blockIdx.x * blockDim.x + threadIdx.x;
    int stride = gridDim.x * blockDim.x;
    for (; i < n; i += stride) dst[i] = f2bf(src[i]);
}

__global__ __launch_bounds__(256, 1) void gru_main(
    const float* __restrict__ x,
    const unsigned short* __restrict__ wih0,
    const unsigned short* __restrict__ whh0,
    const unsigned short* __restrict__ wih1,
    const unsigned short* __restrict__ whh1,
    const float* __restrict__ bih0, const float* __restrict__ bhh0,
    const float* __restrict__ bih1, const float* __restrict__ bhh1,
    const float* __restrict__ wfc,  const float* __restrict__ bfc,
    unsigned short* __restrict__ h0hi, unsigned short* __restrict__ h0lo,
    unsigned short* __restrict__ h1hi, unsigned short* __restrict__ h1lo,
    int* __restrict__ arrive,
    float* __restrict__ out)
{
    const int wg    = blockIdx.x;
    const int layer = wg >> 6;
    const int cc    = wg & 63;
    const int jb    = cc << 4;
    const int tid   = threadIdx.x;
    const int wave  = tid >> 6;
    const int lane  = tid & 63;
    const int l15   = lane & 15;
    const int kg8   = (lane >> 4) << 3;
    const int arow  = (wave << 4) + l15;

    const unsigned short* Whh = layer ? whh1 : whh0;
    const unsigned short* Wih = layer ? wih1 : wih0;
    const float* bih = layer ? bih1 : bih0;
    const float* bhh = layer ? bhh1 : bhh0;
    unsigned short* hhi = layer ? h1hi : h0hi;
    unsigned short* hlo = layer ? h1lo : h0lo;

    const int jg = jb + l15;
    const int KW = layer ? HD : IND;
    const unsigned short* bWR = Whh + (size_t)jg          * HD + kg8;
    const unsigned short* bWZ = Whh + (size_t)(HD   + jg) * HD + kg8;
    const unsigned short* bWN = Whh + (size_t)(2*HD + jg) * HD + kg8;
    const unsigned short* bIR = Wih + (size_t)jg          * KW + kg8;
    const unsigned short* bIZ = Wih + (size_t)(HD   + jg) * KW + kg8;
    const unsigned short* bIN = Wih + (size_t)(2*HD + jg) * KW + kg8;

    const float bias_r  = bih[jg]        + bhh[jg];
    const float bias_z  = bih[HD + jg]   + bhh[HD + jg];
    const float bias_nx = bih[2*HD + jg];
    const float bias_nh = bhh[2*HD + jg];

    for (int iter = 0; iter <= TSEQ; ++iter) {
        const bool active = layer ? (iter >= 1) : (iter < TSEQ);
        if (active) {
            const int t     = layer ? (iter - 1) : iter;
            const int rs    = (t + 1) & 1;
            const int wslot = t & 1;
            const unsigned short* hrhi = hhi + rs * (NB * HD);
            const unsigned short* hrlo = hlo + rs * (NB * HD);

            f32x4 ar  = {0.f, 0.f, 0.f, 0.f};
            f32x4 az  = {0.f, 0.f, 0.f, 0.f};
            f32x4 ahn = {0.f, 0.f, 0.f, 0.f};
            f32x4 axn = {0.f, 0.f, 0.f, 0.f};

            // old h at this thread's 4 output cells (oldest in vmcnt stream)
            unsigned short hoh[4], hol[4];
            #pragma unroll
            for (int e = 0; e < 4; ++e) {
                const int bat = (wave << 4) + ((lane >> 4) << 2) + e;
                hoh[e] = cload16(hrhi + (size_t)bat * HD + jg);
                hol[e] = cload16(hrlo + (size_t)bat * HD + jg);
            }
            CFENCE();   // nothing may sink into the counted region

            const unsigned short* bAh = hrhi + (size_t)arow * HD + kg8;
            const unsigned short* bAl = hrlo + (size_t)arow * HD + kg8;

            if (layer == 0) {
                short8 Wr[4][3];
                short8 Ah[5], Al[5];
#define L0A(c) do { LDA16(Ah[(c)%5], bAh, (c)*64); LDA16(Al[(c)%5], bAl, (c)*64); } while(0)
#define L0W(c) do { LDW16(Wr[(c)&3][0], bWR, (c)*64); LDW16(Wr[(c)&3][1], bWZ, (c)*64); \
                    LDW16(Wr[(c)&3][2], bWN, (c)*64); } while(0)
#define L0MF(c) do { \
    ar  = MFMA(Ah[(c)%5], Wr[(c)&3][0], ar);  ar  = MFMA(Al[(c)%5], Wr[(c)&3][0], ar);  \
    az  = MFMA(Ah[(c)%5], Wr[(c)&3][1], az);  az  = MFMA(Al[(c)%5], Wr[(c)&3][1], az);  \
    ahn = MFMA(Ah[(c)%5], Wr[(c)&3][2], ahn); ahn = MFMA(Al[(c)%5], Wr[(c)&3][2], ahn); } while(0)
#define L0S(c) do { L0W((c)+3); L0A((c)+4); VWAIT(17); L0MF(c); } while(0)
                L0A(0); L0W(0); L0A(1); L0W(1); L0A(2); L0W(2); L0A(3);
                L0S(0);  L0S(1);  L0S(2);  L0S(3);  L0S(4);  L0S(5);  L0S(6);
                L0S(7);  L0S(8);  L0S(9);  L0S(10); L0S(11); L0S(12); L0S(13);
                L0S(14); L0S(15); L0S(16); L0S(17); L0S(18); L0S(19); L0S(20);
                L0S(21); L0S(22); L0S(23); L0S(24); L0S(25); L0S(26); L0S(27);
                L0W(31); VWAIT(15); L0MF(28);
                VWAIT(10); L0MF(29);
                VWAIT(5);  L0MF(30);
                VWAIT(0);  L0MF(31);
                CFENCE();
                // input projection x @ W_ih (K=256): plain cached loads
                const float* px = x + ((size_t)arow * TSEQ + t) * IND + kg8;
                #pragma unroll
                for (int k = 0; k < 8; ++k) {
                    float4 xa = *(const float4*)(px + k * 32);
                    float4 xc = *(const float4*)(px + k * 32 + 4);
                    short8 af;
                    af[0] = (short)f2bf(xa.x); af[1] = (short)f2bf(xa.y);
                    af[2] = (short)f2bf(xa.z); af[3] = (short)f2bf(xa.w);
                    af[4] = (short)f2bf(xc.x); af[5] = (short)f2bf(xc.y);
                    af[6] = (short)f2bf(xc.z); af[7] = (short)f2bf(xc.w);
                    short8 br = *(const short8*)(bIR + k * 32);
                    short8 bz = *(const short8*)(bIZ + k * 32);
                    short8 bn = *(const short8*)(bIN + k * 32);
                    ar  = MFMA(af, br, ar);
                    az  = MFMA(af, bz, az);
                    axn = MFMA(af, bn, axn);
                }
            } else {
                const unsigned short* bAy = h0hi + (size_t)wslot * (NB * HD)
                                                 + (size_t)arow * HD + kg8;
                short8 Wr[4][6];
                short8 Ah[5], Al[5], Ay[5];
#define L1A(c) do { LDA16(Ah[(c)%5], bAh, (c)*64); LDA16(Al[(c)%5], bAl, (c)*64); \
                    LDA16(Ay[(c)%5], bAy, (c)*64); } while(0)
#define L1W(c) do { LDW16(Wr[(c)&3][0], bWR, (c)*64); LDW16(Wr[(c)&3][1], bWZ, (c)*64); \
                    LDW16(Wr[(c)&3][2], bWN, (c)*64); LDW16(Wr[(c)&3][3], bIR, (c)*64); \
                    LDW16(Wr[(c)&3][4], bIZ, (c)*64); LDW16(Wr[(c)&3][5], bIN, (c)*64); } while(0)
#define L1MF(c) do { \
    ar  = MFMA(Ah[(c)%5], Wr[(c)&3][0], ar);  ar  = MFMA(Al[(c)%5], Wr[(c)&3][0], ar);  \
    ar  = MFMA(Ay[(c)%5], Wr[(c)&3][3], ar); \
    az  = MFMA(Ah[(c)%5], Wr[(c)&3][1], az);  az  = MFMA(Al[(c)%5], Wr[(c)&3][1], az);  \
    az  = MFMA(Ay[(c)%5], Wr[(c)&3][4], az); \
    ahn = MFMA(Ah[(c)%5], Wr[(c)&3][2], ahn); ahn = MFMA(Al[(c)%5], Wr[(c)&3][2], ahn); \
    axn = MFMA(Ay[(c)%5], Wr[(c)&3][5], axn); } while(0)
#define L1S(c) do { L1W((c)+3); L1A((c)+4); VWAIT(30); L1MF(c); } while(0)
                L1A(0); L1W(0); L1A(1); L1W(1); L1A(2); L1W(2); L1A(3);
                L1S(0);  L1S(1);  L1S(2);  L1S(3);  L1S(4);  L1S(5);  L1S(6);
                L1S(7);  L1S(8);  L1S(9);  L1S(10); L1S(11); L1S(12); L1S(13);
                L1S(14); L1S(15); L1S(16); L1S(17); L1S(18); L1S(19); L1S(20);
                L1S(21); L1S(22); L1S(23); L1S(24); L1S(25); L1S(26); L1S(27);
                L1W(31); VWAIT(27); L1MF(28);
                VWAIT(18); L1MF(29);
                VWAIT(9);  L1MF(30);
                VWAIT(0);  L1MF(31);
                CFENCE();
            }

            // ---- gates + state update + coherent (write-through) store ----
            unsigned short* hwhi = hhi + wslot * (NB * HD);
            unsigned short* hwlo = hlo + wslot * (NB * HD);
            #pragma unroll
            for (int e = 0; e < 4; ++e) {
                const int bat = (wave << 4) + ((lane >> 4) << 2) + e;
                const size_t idx = (size_t)bat * HD + jg;
                float r = sigm(ar[e] + bias_r);
                float z = sigm(az[e] + bias_z);
                float n = tanh_fast(axn[e] + bias_nx + r * (ahn[e] + bias_nh));
                float hold = bf2f((unsigned)hoh[e]) + bf2f((unsigned)hol[e]);
                float hnew = (1.0f - z) * n + z * hold;
                unsigned short hi_ = f2bf(hnew);
                cstore16(hwhi + idx, hi_);
                cstore16(hwlo + idx, f2bf(hnew - bf2f((unsigned)hi_)));
            }
        }

        // ---- barrier: drain stores, count arrivals at L3, single poller ----
        asm volatile("s_waitcnt vmcnt(0)" ::: "memory");
        __syncthreads();
        if (tid == 0) {
            atomicAdd(&arrive[iter * FS], 1);
            int spins = 0;
            while (__hip_atomic_load(&arrive[iter * FS],
                                     __ATOMIC_RELAXED, __HIP_MEMORY_SCOPE_AGENT) < NWG) {
                __builtin_amdgcn_s_sleep(1);
                if (++spins > (1 << 20)) break;
            }
        }
        __syncthreads();
    }

    // ---- deterministic FC tail (single WG, coherent reads) ----
    if (wg == 64) {
        const int fslot = (TSEQ - 1) & 1;
        const unsigned short* hf_hi = h1hi + (size_t)fslot * (NB * HD);
        const unsigned short* hf_lo = h1lo + (size_t)fslot * (NB * HD);
        const int bat  = tid & 63;
        const int part = tid >> 6;
        const int k0   = part * (HD / 4);
        float s = 0.0f;
        for (int k = 0; k < HD / 4; ++k) {
            size_t idx = (size_t)bat * HD + k0 + k;
            s += (bf2f((unsigned)cload16(hf_hi + idx)) +
                  bf2f((unsigned)cload16(hf_lo + idx))) * wfc[k0 + k];
        }
        __shared__ float red[256];
        red[tid] = s;
        __syncthreads();
        if (tid < 64)
            out[tid] = red[tid] + red[tid + 64] + red[tid + 128] + red[tid + 192] + bfc[0];
    }
}

extern "C" void kernel_launch(void* const* d_in, const int* in_sizes, int n_in,
                              void* d_out, int out_size, void* d_ws, size_t ws_size,
                              hipStream_t stream) {
    const float* x    = (const float*)d_in[0];
    const float* Wih0 = (const float*)d_in[1];
    const float* Whh0 = (const float*)d_in[2];
    const float* bih0 = (const float*)d_in[3];
    const float* bhh0 = (const float*)d_in[4];
    const float* Wih1 = (const float*)d_in[5];
    const float* Whh1 = (const float*)d_in[6];
    const float* bih1 = (const float*)d_in[7];
    const float* bhh1 = (const float*)d_in[8];
    const float* Wfc  = (const float*)d_in[9];
    const float* bfc  = (const float*)d_in[10];
    float* out = (float*)d_out;

    char* ws = (char*)d_ws;
    size_t off = 0;
    int* arrive = (int*)(ws + off);                off += (size_t)(TSEQ + 1) * FS * 4;
    unsigned short* h0hi = (unsigned short*)(ws + off); off += (size_t)2 * NB * HD * 2;
    unsigned short* h0lo = (unsigned short*)(ws + off); off += (size_t)2 * NB * HD * 2;
    unsigned short* h1hi = (unsigned short*)(ws + off); off += (size_t)2 * NB * HD * 2;
    unsigned short* h1lo = (unsigned short*)(ws + off); off += (size_t)2 * NB * HD * 2;
    size_t zero_bytes = off;
    unsigned short* wih0b = (unsigned short*)(ws + off); off += (size_t)3 * HD * IND * 2;
    unsigned short* whh0b = (unsigned short*)(ws + off); off += (size_t)3 * HD * HD * 2;
    unsigned short* wih1b = (unsigned short*)(ws + off); off += (size_t)3 * HD * HD * 2;
    unsigned short* whh1b = (unsigned short*)(ws + off); off += (size_t)3 * HD * HD * 2;
    if (off > ws_size) return;

    hipMemsetAsync(d_ws, 0, zero_bytes, stream);
    hipMemsetAsync(d_out, 0, (size_t)out_size * sizeof(float), stream);

    convert_w<<<512, 256, 0, stream>>>(Wih0, wih0b, 3 * HD * IND);
    convert_w<<<512, 256, 0, stream>>>(Whh0, whh0b, 3 * HD * HD);
    convert_w<<<512, 256, 0, stream>>>(Wih1, wih1b, 3 * HD * HD);
    convert_w<<<512, 256, 0, stream>>>(Whh1, whh1b, 3 * HD * HD);

    gru_main<<<NWG, 256, 0, stream>>>(x, wih0b, whh0b, wih1b, whh1b,
                                      bih0, bhh0, bih1, bhh1, Wfc, bfc,
                                      h0hi, h0lo, h1hi, h1lo, arrive, out);
}